// Round 3
// baseline (2280.808 us; speedup 1.0000x reference)
//
#include <hip/hip_runtime.h>

typedef unsigned short u16;
typedef unsigned int u32;
typedef __attribute__((ext_vector_type(8))) short short8;
typedef __attribute__((ext_vector_type(4))) float f32x4;

#define NN 100000
#define PAD 640

__device__ __forceinline__ float b2f(u16 u) {
    union { u32 i; float f; } v; v.i = ((u32)u) << 16; return v.f;
}
__device__ __forceinline__ u16 f2b(float f) {
    union { float f; u32 i; } v; v.f = f;
    u32 x = v.i;
    return (u16)((x + 0x7FFFu + ((x >> 16) & 1u)) >> 16);
}
// read element i of a float tensor that is fp32 (f=1) or bf16 (f=0) on the wire
__device__ __forceinline__ float rdf(const void* p, size_t i, int f) {
    return f ? ((const float*)p)[i] : b2f(((const u16*)p)[i]);
}

// ---------------- dtype probes ----------------
// flags[0]: adj_index is int64 (odd int32 slots of first 128 entries all zero)
// flags[1..8]: tensor {avals,feats,W1,b1,W2,b2,Wfc,bfc} is fp32.
//   True-bf16 data here has |v| < 64 -> exp field <= 132. fp32-as-u16 even
//   slots are random mantissa bits: ~48% have exp >= 133.
__global__ void probe_k(const int* __restrict__ idx,
                        const void* avals, const void* feats, const void* W1,
                        const void* b1, const void* W2, const void* b2,
                        const void* Wfc, const void* bfc,
                        int* __restrict__ flags) {
    if (threadIdx.x != 0 || blockIdx.x != 0) return;
    int z = 1;
    for (int i = 0; i < 128; ++i)
        if (idx[2 * i + 1] != 0) { z = 0; break; }
    flags[0] = z;
    const void* ts[8] = {avals, feats, W1, b1, W2, b2, Wfc, bfc};
    const int ns[8] = {256, 256, 256, 128, 256, 128, 256, 32};
    for (int t = 0; t < 8; ++t) {
        const u16* p = (const u16*)ts[t];
        int n = ns[t], bad = 0;
        for (int i = 0; i < n; ++i) {
            int e = (p[2 * i] >> 7) & 0xFF;
            if (e >= 133) bad++;
        }
        flags[1 + t] = (bad * 8 >= n) ? 1 : 0;
    }
}

__device__ __forceinline__ int load_row(const int* idx, int E, int f, int e) {
    return f ? idx[2 * e] : idx[e];
}
__device__ __forceinline__ int load_col(const int* idx, int E, int f, int e) {
    return f ? idx[2 * E + 2 * e] : idx[E + e];
}

// ---------------- canonicalize inputs ----------------
__global__ void featconv_k(const void* __restrict__ src, u16* __restrict__ dst,
                           const int* __restrict__ flags) {
    int i = blockIdx.x * 256 + threadIdx.x;
    if (i >= NN * 512) return;
    int f = flags[2];
    dst[i] = f ? f2b(((const float*)src)[i]) : ((const u16*)src)[i];
}
// W1 [3,512,200] -> w1t [640][512]
__global__ void w1t_k(const void* __restrict__ W1, u16* __restrict__ w1t,
                      const int* __restrict__ flags) {
    int i = blockIdx.x * 256 + threadIdx.x;
    if (i >= 640 * 512) return;
    int n = i >> 9, k = i & 511;
    float v = 0.f;
    if (n < 600) {
        int ib = n / 200, c = n % 200;
        v = rdf(W1, (size_t)ib * 102400 + (size_t)k * 200 + c, flags[3]);
    }
    w1t[i] = f2b(v);
}
// W2 [3,600,200] -> w2t [640][640]
__global__ void w2t_k(const void* __restrict__ W2, u16* __restrict__ w2t,
                      const int* __restrict__ flags) {
    int i = blockIdx.x * 256 + threadIdx.x;
    if (i >= 640 * 640) return;
    int n = i / 640, k = i % 640;
    float v = 0.f;
    if (n < 600 && k < 600) {
        int ib = n / 200, c = n % 200;
        v = rdf(W2, (size_t)ib * 120000 + (size_t)k * 200 + c, flags[5]);
    }
    w2t[i] = f2b(v);
}
// Wfc [600,64] -> wfct [64][640]
__global__ void wfct_k(const void* __restrict__ Wfc, u16* __restrict__ wfct,
                       const int* __restrict__ flags) {
    int i = blockIdx.x * 256 + threadIdx.x;
    if (i >= 64 * 640) return;
    int n = i / 640, k = i % 640;
    float v = 0.f;
    if (k < 600) v = rdf(Wfc, (size_t)k * 64 + n, flags[7]);
    wfct[i] = f2b(v);
}
// biases -> fp32: [0,600)=b1, [600,1200)=b2, [1200,1264)=bfc
__global__ void bconv_k(const void* __restrict__ b1, const void* __restrict__ b2,
                        const void* __restrict__ bfc, float* __restrict__ o,
                        const int* __restrict__ flags) {
    int i = blockIdx.x * 256 + threadIdx.x;
    if (i < 600) o[i] = rdf(b1, i, flags[4]);
    else if (i < 1200) o[i] = rdf(b2, i - 600, flags[6]);
    else if (i < 1264) o[i] = rdf(bfc, i - 1200, flags[8]);
}

// ---------------- CSR build ----------------
__global__ void count_k(const int* __restrict__ idx, int E, const int* __restrict__ flags,
                        int* __restrict__ counts) {
    int e = blockIdx.x * 256 + threadIdx.x;
    if (e >= E) return;
    int r = load_row(idx, E, flags[0], e);
    if ((u32)r >= NN) return;
    atomicAdd(&counts[r], 1);
}

__global__ void chunksum_k(const int* __restrict__ counts, int* __restrict__ chsum) {
    __shared__ int sm[256];
    int c = blockIdx.x, t = threadIdx.x;
    int base = c * 1024, s = 0;
    for (int i = t; i < 1024; i += 256) {
        int g = base + i;
        if (g < NN) s += counts[g];
    }
    sm[t] = s; __syncthreads();
    for (int off = 128; off; off >>= 1) {
        if (t < off) sm[t] += sm[t + off];
        __syncthreads();
    }
    if (t == 0) chsum[c] = sm[0];
}

__global__ void chscan_k(const int* __restrict__ chsum, int nch, int* __restrict__ choff,
                         int* __restrict__ row_ptr, int E) {
    if (threadIdx.x == 0 && blockIdx.x == 0) {
        int run = 0;
        for (int c = 0; c < nch; ++c) { choff[c] = run; run += chsum[c]; }
        row_ptr[NN] = run;
    }
}

__global__ __launch_bounds__(1024) void scan_k(const int* __restrict__ counts,
                                               const int* __restrict__ choff,
                                               int* __restrict__ row_ptr,
                                               int* __restrict__ cursor) {
    __shared__ int sm[1024];
    int c = blockIdx.x, t = threadIdx.x;
    int g = c * 1024 + t;
    int v = (g < NN) ? counts[g] : 0;
    sm[t] = v;
    __syncthreads();
    for (int off = 1; off < 1024; off <<= 1) {
        int add = (t >= off) ? sm[t - off] : 0;
        __syncthreads();
        sm[t] += add;
        __syncthreads();
    }
    if (g < NN) {
        int ex = choff[c] + sm[t] - v;
        row_ptr[g] = ex;
        cursor[g] = ex;
    }
}

__global__ void scatter_k(const int* __restrict__ idx, const void* __restrict__ avals, int E,
                          const int* __restrict__ flags, int* __restrict__ cursor,
                          int* __restrict__ colsS, float* __restrict__ valsS) {
    int e = blockIdx.x * 256 + threadIdx.x;
    if (e >= E) return;
    int f = flags[0];
    int r = load_row(idx, E, f, e);
    if ((u32)r >= NN) return;
    int c = load_col(idx, E, f, e);
    if ((u32)c >= NN) c = 0;
    int p = atomicAdd(&cursor[r], 1);
    colsS[p] = c;
    valsS[p] = rdf(avals, e, flags[1]);
}

// ---------------- bf16 MFMA GEMM: C[M x Ntiles*64] = A[M x K] * Bt[N x K]^T --------------
__global__ __launch_bounds__(256) void gemm_k(
    const u16* __restrict__ A, const u16* __restrict__ Bt,
    u16* __restrict__ C, float* __restrict__ Cf,
    const float* __restrict__ bias, int bias_n, int relu,
    int M, int K, int lda, int ldc) {
    __shared__ u16 As[64][40];
    __shared__ u16 Bs[64][40];
    const int tid = threadIdx.x;
    const int wave = tid >> 6, lane = tid & 63;
    const int bm = blockIdx.x * 64, bn = blockIdx.y * 64;
    const int wr = (wave >> 1) * 32, wc = (wave & 1) * 32;
    const int l15 = lane & 15, l4 = lane >> 4;
    f32x4 acc[2][2] = {};

    const int srow = tid >> 2;
    const int skoff = (tid & 3) * 8;
    const bool arow_ok = (bm + srow) < M;
    const u16* aptr = A + (size_t)(bm + srow) * lda + skoff;
    const u16* bptr = Bt + (size_t)(bn + srow) * K + skoff;

    for (int k0 = 0; k0 < K; k0 += 32) {
        short8 av = {};
        if (arow_ok) av = *(const short8*)(aptr + k0);
        short8 bv = *(const short8*)(bptr + k0);
        __syncthreads();
        *(short8*)&As[srow][skoff] = av;
        *(short8*)&Bs[srow][skoff] = bv;
        __syncthreads();
        short8 a0 = *(const short8*)&As[wr + l15][l4 * 8];
        short8 a1 = *(const short8*)&As[wr + 16 + l15][l4 * 8];
        short8 bb0 = *(const short8*)&Bs[wc + l15][l4 * 8];
        short8 bb1 = *(const short8*)&Bs[wc + 16 + l15][l4 * 8];
        acc[0][0] = __builtin_amdgcn_mfma_f32_16x16x32_bf16(a0, bb0, acc[0][0], 0, 0, 0);
        acc[0][1] = __builtin_amdgcn_mfma_f32_16x16x32_bf16(a0, bb1, acc[0][1], 0, 0, 0);
        acc[1][0] = __builtin_amdgcn_mfma_f32_16x16x32_bf16(a1, bb0, acc[1][0], 0, 0, 0);
        acc[1][1] = __builtin_amdgcn_mfma_f32_16x16x32_bf16(a1, bb1, acc[1][1], 0, 0, 0);
    }

#pragma unroll
    for (int mi = 0; mi < 2; ++mi)
#pragma unroll
        for (int ni = 0; ni < 2; ++ni)
#pragma unroll
            for (int r = 0; r < 4; ++r) {
                int row = bm + wr + mi * 16 + l4 * 4 + r;
                int col = bn + wc + ni * 16 + l15;
                if (row < M) {
                    float v = acc[mi][ni][r];
                    if (bias && col < bias_n) v += bias[col];
                    if (relu) v = fmaxf(v, 0.0f);
                    if (C) C[(size_t)row * ldc + col] = f2b(v);
                    if (Cf) Cf[(size_t)row * ldc + col] = v;
                }
            }
}

// ---------------- CSR spmm: Y[r,:200] = sum val * X[col,:200] (+bias) ----------------
__global__ __launch_bounds__(256) void spmm_k(
    const int* __restrict__ row_ptr, const int* __restrict__ cols,
    const float* __restrict__ vals, int E,
    const u16* __restrict__ X, int ldx,
    u16* __restrict__ Y, int ldy,
    const float* __restrict__ bias) {
    int r = blockIdx.x * 4 + (threadIdx.x >> 6);
    if (r >= NN) return;
    int lane = threadIdx.x & 63;
    float a0 = 0.f, a1 = 0.f, a2 = 0.f, a3 = 0.f;
    int s = row_ptr[r], e = row_ptr[r + 1];
    if (e > E) e = E;
    if (s < 0) s = 0;
    if (s > e) s = e;
    for (int i = s; i < e; ++i) {
        int c = cols[i];
        if ((u32)c >= NN) c = 0;
        float v = vals[i];
        const u16* xr = X + (size_t)c * ldx;
        a0 += v * b2f(xr[lane]);
        a1 += v * b2f(xr[lane + 64]);
        a2 += v * b2f(xr[lane + 128]);
        if (lane < 8) a3 += v * b2f(xr[lane + 192]);
    }
    if (bias) {
        a0 += bias[lane];
        a1 += bias[lane + 64];
        a2 += bias[lane + 128];
        if (lane < 8) a3 += bias[lane + 192];
    }
    u16* yr = Y + (size_t)r * ldy;
    yr[lane] = f2b(a0);
    yr[lane + 64] = f2b(a1);
    yr[lane + 128] = f2b(a2);
    if (lane < 8) yr[lane + 192] = f2b(a3);
}

// ---------------- copies ----------------
__global__ void copyblk_k(const u16* __restrict__ src, u16* __restrict__ dst) {
    int i = blockIdx.x * 256 + threadIdx.x;
    if (i >= NN * 100) return;
    int r = i / 100, c = i % 100;
    ((u32*)dst)[(size_t)r * 320 + c] = ((const u32*)src)[(size_t)r * 320 + c];
}
__global__ void zeropad_k(u16* __restrict__ dst) {
    int i = blockIdx.x * 256 + threadIdx.x;
    if (i >= NN * 20) return;
    int r = i / 20, c = i % 20;
    ((u32*)dst)[(size_t)r * 320 + 300 + c] = 0u;
}
__global__ void copybias_k(const u16* __restrict__ src, u16* __restrict__ dst,
                           const float* __restrict__ bias) {
    int i = blockIdx.x * 256 + threadIdx.x;
    if (i >= NN * 200) return;
    int r = i / 200, c = i % 200;
    dst[(size_t)r * 640 + c] = f2b(b2f(src[(size_t)r * 640 + c]) + bias[c]);
}

// ---------------- log_softmax over 64 classes, one wave per row (fp32 in/out) -----------
__global__ void softmax_k(const float* __restrict__ ne, float* __restrict__ out) {
    int r = blockIdx.x * 4 + (threadIdx.x >> 6);
    if (r >= NN) return;
    int lane = threadIdx.x & 63;
    float v = ne[(size_t)r * 64 + lane];
    float m = v;
    for (int off = 32; off; off >>= 1) m = fmaxf(m, __shfl_xor(m, off, 64));
    float e = expf(v - m);
    float ssum = e;
    for (int off = 32; off; off >>= 1) ssum += __shfl_xor(ssum, off, 64);
    out[(size_t)r * 64 + lane] = v - m - logf(ssum);
}

extern "C" void kernel_launch(void* const* d_in, const int* in_sizes, int n_in,
                              void* d_out, int out_size, void* d_ws, size_t ws_size,
                              hipStream_t stream) {
    const int* adj_idx = (const int*)d_in[0];
    const void* adj_vals = d_in[1];
    const void* feats = d_in[2];
    const void* W1 = d_in[3];
    const void* b1 = d_in[4];
    const void* W2 = d_in[5];
    const void* b2 = d_in[6];
    const void* Wfc = d_in[7];
    const void* bfc = d_in[8];
    const int E = in_sizes[1];
    (void)n_in; (void)out_size; (void)ws_size;

    char* ws = (char*)d_ws;
    size_t off = 0;
    auto alloc = [&](size_t b) { size_t o = off; off += (b + 255) & ~(size_t)255; return o; };
    u16* buf0 = (u16*)(ws + alloc((size_t)NN * PAD * 2));   // U, then V
    u16* buf1 = (u16*)(ws + alloc((size_t)NN * PAD * 2));   // featsB, abstract1, abstract2
    u16* hop = (u16*)(ws + alloc((size_t)NN * 200 * 2));
    u16* w1t = (u16*)(ws + alloc((size_t)640 * 512 * 2));
    u16* w2t = (u16*)(ws + alloc((size_t)640 * 640 * 2));
    u16* wfct = (u16*)(ws + alloc((size_t)64 * 640 * 2));
    float* biasf = (float*)(ws + alloc(1264 * 4));
    int* counts = (int*)(ws + alloc((size_t)NN * 4));
    int* cursor = (int*)(ws + alloc((size_t)NN * 4));
    int* row_ptr = (int*)(ws + alloc((size_t)(NN + 1) * 4));
    int* chsum = (int*)(ws + alloc(4096));
    int* choff = (int*)(ws + alloc(4096));
    int* flags = (int*)(ws + alloc(256));
    int* colsS = (int*)(ws + alloc((size_t)E * 4));
    float* valsS = (float*)(ws + alloc((size_t)E * 4));

    u16* featsB = buf1;  // alias: featsB dead after GEMM1, buf1 written after
    float* out_ne = (float*)d_out;              // fp32 node_emb
    float* out_pred = out_ne + (size_t)NN * 64; // fp32 log-softmax

    // probes + canonicalization
    probe_k<<<1, 64, 0, stream>>>(adj_idx, adj_vals, feats, W1, b1, W2, b2, Wfc, bfc, flags);
    featconv_k<<<(NN * 512 + 255) / 256, 256, 0, stream>>>(feats, featsB, flags);
    w1t_k<<<(640 * 512 + 255) / 256, 256, 0, stream>>>(W1, w1t, flags);
    w2t_k<<<(640 * 640 + 255) / 256, 256, 0, stream>>>(W2, w2t, flags);
    wfct_k<<<(64 * 640 + 255) / 256, 256, 0, stream>>>(Wfc, wfct, flags);
    bconv_k<<<5, 256, 0, stream>>>(b1, b2, bfc, biasf, flags);

    // CSR build
    hipMemsetAsync(counts, 0, NN * 4, stream);
    count_k<<<(E + 255) / 256, 256, 0, stream>>>(adj_idx, E, flags, counts);
    const int NCH = (NN + 1023) / 1024;  // 98
    chunksum_k<<<NCH, 256, 0, stream>>>(counts, chsum);
    chscan_k<<<1, 64, 0, stream>>>(chsum, NCH, choff, row_ptr, E);
    scan_k<<<NCH, 1024, 0, stream>>>(counts, choff, row_ptr, cursor);
    scatter_k<<<(E + 255) / 256, 256, 0, stream>>>(adj_idx, adj_vals, E, flags, cursor, colsS, valsS);

    dim3 gA((NN + 63) / 64, PAD / 64);
    // U = relu(X @ W1all + b1) -> buf0
    gemm_k<<<gA, 256, 0, stream>>>(featsB, w1t, buf0, nullptr, biasf, 600, 1, NN, 512, 512, PAD);
    // abstract1 -> buf1
    copyblk_k<<<(NN * 100 + 255) / 256, 256, 0, stream>>>(buf0, buf1);
    zeropad_k<<<(NN * 20 + 255) / 256, 256, 0, stream>>>(buf1);
    spmm_k<<<(NN + 3) / 4, 256, 0, stream>>>(row_ptr, colsS, valsS, E, buf0 + 200, PAD, buf1 + 200, PAD, nullptr);
    spmm_k<<<(NN + 3) / 4, 256, 0, stream>>>(row_ptr, colsS, valsS, E, buf0 + 400, PAD, hop, 200, nullptr);
    spmm_k<<<(NN + 3) / 4, 256, 0, stream>>>(row_ptr, colsS, valsS, E, hop, 200, buf1 + 400, PAD, nullptr);
    // V = abstract1 @ W2all -> buf0
    gemm_k<<<gA, 256, 0, stream>>>(buf1, w2t, buf0, nullptr, nullptr, 0, 0, NN, PAD, PAD, PAD);
    // abstract2 -> buf1
    copybias_k<<<(NN * 200 + 255) / 256, 256, 0, stream>>>(buf0, buf1, biasf + 600);
    spmm_k<<<(NN + 3) / 4, 256, 0, stream>>>(row_ptr, colsS, valsS, E, buf0 + 200, PAD, buf1 + 200, PAD, biasf + 800);
    spmm_k<<<(NN + 3) / 4, 256, 0, stream>>>(row_ptr, colsS, valsS, E, buf0 + 400, PAD, hop, 200, nullptr);
    spmm_k<<<(NN + 3) / 4, 256, 0, stream>>>(row_ptr, colsS, valsS, E, hop, 200, buf1 + 400, PAD, biasf + 1000);
    // node_emb = abstract2 @ Wfc + bfc -> d_out (fp32)
    dim3 gC((NN + 63) / 64, 1);
    gemm_k<<<gC, 256, 0, stream>>>(buf1, wfct, nullptr, out_ne, biasf + 1200, 64, 0, NN, PAD, PAD, 64);
    // predictions = log_softmax(node_emb) (fp32)
    softmax_k<<<(NN + 3) / 4, 256, 0, stream>>>(out_ne, out_pred);
}

// Round 4
// 1727.432 us; speedup vs baseline: 1.3203x; 1.3203x over previous
//
#include <hip/hip_runtime.h>

typedef unsigned short u16;
typedef unsigned int u32;
typedef __attribute__((ext_vector_type(8))) short short8;
typedef __attribute__((ext_vector_type(4))) float f32x4;
typedef __attribute__((ext_vector_type(4))) u32 u32x4;
typedef __attribute__((ext_vector_type(2))) u32 u32x2;

#define NN 100000
#define PAD 640

__device__ __forceinline__ float b2f(u16 u) {
    union { u32 i; float f; } v; v.i = ((u32)u) << 16; return v.f;
}
__device__ __forceinline__ u16 f2b(float f) {
    union { float f; u32 i; } v; v.f = f;
    u32 x = v.i;
    return (u16)((x + 0x7FFFu + ((x >> 16) & 1u)) >> 16);
}
__device__ __forceinline__ u32 pack2(float lo, float hi) {
    return (u32)f2b(lo) | ((u32)f2b(hi) << 16);
}
// read element i of a float tensor that is fp32 (f=1) or bf16 (f=0) on the wire
__device__ __forceinline__ float rdf(const void* p, size_t i, int f) {
    return f ? ((const float*)p)[i] : b2f(((const u16*)p)[i]);
}
// async global->LDS, 16B per lane; lptr must be wave-uniform
__device__ __forceinline__ void gload16(const u16* g, u16* l) {
    __builtin_amdgcn_global_load_lds(
        (const __attribute__((address_space(1))) void*)g,
        (__attribute__((address_space(3))) void*)l, 16, 0, 0);
}

// ---------------- dtype probes ----------------
__global__ void probe_k(const int* __restrict__ idx,
                        const void* avals, const void* feats, const void* W1,
                        const void* b1, const void* W2, const void* b2,
                        const void* Wfc, const void* bfc,
                        int* __restrict__ flags) {
    if (threadIdx.x != 0 || blockIdx.x != 0) return;
    int z = 1;
    for (int i = 0; i < 128; ++i)
        if (idx[2 * i + 1] != 0) { z = 0; break; }
    flags[0] = z;
    const void* ts[8] = {avals, feats, W1, b1, W2, b2, Wfc, bfc};
    const int ns[8] = {256, 256, 256, 128, 256, 128, 256, 32};
    for (int t = 0; t < 8; ++t) {
        const u16* p = (const u16*)ts[t];
        int n = ns[t], bad = 0;
        for (int i = 0; i < n; ++i) {
            int e = (p[2 * i] >> 7) & 0xFF;
            if (e >= 133) bad++;
        }
        flags[1 + t] = (bad * 8 >= n) ? 1 : 0;
    }
}

__device__ __forceinline__ int load_row(const int* idx, int E, int f, int e) {
    return f ? idx[2 * e] : idx[e];
}
__device__ __forceinline__ int load_col(const int* idx, int E, int f, int e) {
    return f ? idx[2 * E + 2 * e] : idx[E + e];
}

// ---------------- canonicalize inputs ----------------
__global__ void featconv_k(const void* __restrict__ src, u16* __restrict__ dst,
                           const int* __restrict__ flags) {
    int i = blockIdx.x * 256 + threadIdx.x;
    if (i >= NN * 512) return;
    int f = flags[2];
    dst[i] = f ? f2b(((const float*)src)[i]) : ((const u16*)src)[i];
}
__global__ void w1t_k(const void* __restrict__ W1, u16* __restrict__ w1t,
                      const int* __restrict__ flags) {
    int i = blockIdx.x * 256 + threadIdx.x;
    if (i >= 640 * 512) return;
    int n = i >> 9, k = i & 511;
    float v = 0.f;
    if (n < 600) {
        int ib = n / 200, c = n % 200;
        v = rdf(W1, (size_t)ib * 102400 + (size_t)k * 200 + c, flags[3]);
    }
    w1t[i] = f2b(v);
}
__global__ void w2t_k(const void* __restrict__ W2, u16* __restrict__ w2t,
                      const int* __restrict__ flags) {
    int i = blockIdx.x * 256 + threadIdx.x;
    if (i >= 640 * 640) return;
    int n = i / 640, k = i % 640;
    float v = 0.f;
    if (n < 600 && k < 600) {
        int ib = n / 200, c = n % 200;
        v = rdf(W2, (size_t)ib * 120000 + (size_t)k * 200 + c, flags[5]);
    }
    w2t[i] = f2b(v);
}
__global__ void wfct_k(const void* __restrict__ Wfc, u16* __restrict__ wfct,
                       const int* __restrict__ flags) {
    int i = blockIdx.x * 256 + threadIdx.x;
    if (i >= 64 * 640) return;
    int n = i / 640, k = i % 640;
    float v = 0.f;
    if (k < 600) v = rdf(Wfc, (size_t)k * 64 + n, flags[7]);
    wfct[i] = f2b(v);
}
__global__ void bconv_k(const void* __restrict__ b1, const void* __restrict__ b2,
                        const void* __restrict__ bfc, float* __restrict__ o,
                        const int* __restrict__ flags) {
    int i = blockIdx.x * 256 + threadIdx.x;
    if (i < 600) o[i] = rdf(b1, i, flags[4]);
    else if (i < 1200) o[i] = rdf(b2, i - 600, flags[6]);
    else if (i < 1264) o[i] = rdf(bfc, i - 1200, flags[8]);
}

// ---------------- CSR build ----------------
__global__ void count_k(const int* __restrict__ idx, int E, const int* __restrict__ flags,
                        int* __restrict__ counts) {
    int e = blockIdx.x * 256 + threadIdx.x;
    if (e >= E) return;
    int r = load_row(idx, E, flags[0], e);
    if ((u32)r >= NN) return;
    atomicAdd(&counts[r], 1);
}

__global__ void chunksum_k(const int* __restrict__ counts, int* __restrict__ chsum) {
    __shared__ int sm[256];
    int c = blockIdx.x, t = threadIdx.x;
    int base = c * 1024, s = 0;
    for (int i = t; i < 1024; i += 256) {
        int g = base + i;
        if (g < NN) s += counts[g];
    }
    sm[t] = s; __syncthreads();
    for (int off = 128; off; off >>= 1) {
        if (t < off) sm[t] += sm[t + off];
        __syncthreads();
    }
    if (t == 0) chsum[c] = sm[0];
}

__global__ void chscan_k(const int* __restrict__ chsum, int nch, int* __restrict__ choff,
                         int* __restrict__ row_ptr, int E) {
    if (threadIdx.x == 0 && blockIdx.x == 0) {
        int run = 0;
        for (int c = 0; c < nch; ++c) { choff[c] = run; run += chsum[c]; }
        row_ptr[NN] = run;
    }
}

__global__ __launch_bounds__(1024) void scan_k(const int* __restrict__ counts,
                                               const int* __restrict__ choff,
                                               int* __restrict__ row_ptr,
                                               int* __restrict__ cursor) {
    __shared__ int sm[1024];
    int c = blockIdx.x, t = threadIdx.x;
    int g = c * 1024 + t;
    int v = (g < NN) ? counts[g] : 0;
    sm[t] = v;
    __syncthreads();
    for (int off = 1; off < 1024; off <<= 1) {
        int add = (t >= off) ? sm[t - off] : 0;
        __syncthreads();
        sm[t] += add;
        __syncthreads();
    }
    if (g < NN) {
        int ex = choff[c] + sm[t] - v;
        row_ptr[g] = ex;
        cursor[g] = ex;
    }
}

__global__ void scatter_k(const int* __restrict__ idx, const void* __restrict__ avals, int E,
                          const int* __restrict__ flags, int* __restrict__ cursor,
                          int* __restrict__ colsS, float* __restrict__ valsS) {
    int e = blockIdx.x * 256 + threadIdx.x;
    if (e >= E) return;
    int f = flags[0];
    int r = load_row(idx, E, f, e);
    if ((u32)r >= NN) return;
    int c = load_col(idx, E, f, e);
    if ((u32)c >= NN) c = 0;
    int p = atomicAdd(&cursor[r], 1);
    colsS[p] = c;
    valsS[p] = rdf(avals, e, flags[1]);
}

// ---------------- 128x128 MFMA GEMM with global_load_lds (m97 structure) ----------------
// C[M x N] = A[M x K] * Bt[N x K]^T ; N multiple of 128; K multiple of 32
__global__ __launch_bounds__(256) void gemm128_k(
    const u16* __restrict__ A, const u16* __restrict__ Bt,
    u16* __restrict__ C, float* __restrict__ Cf,
    const float* __restrict__ bias, int bias_n, int relu,
    int M, int K, int lda, int ldc) {
    __shared__ u16 As[128 * 32];
    __shared__ u16 Bs[128 * 32];
    const int tid = threadIdx.x;
    const int wave = tid >> 6, lane = tid & 63;
    const int bm = blockIdx.x * 128, bn = blockIdx.y * 128;
    const int wrow = (wave >> 1) * 64, wcol = (wave & 1) * 64;
    const int l15 = lane & 15, l4 = lane >> 4;
    f32x4 acc[4][4] = {};

    // staging: wave w covers chunks 2w, 2w+1 of each 8KB tile (1KB per wave-issue)
    const int c0 = wave * 2;
    const int rowA0 = c0 * 16 + (lane >> 2);
    const int rowA1 = rowA0 + 16;
    const int colE = (lane & 3) * 8;
    int gr0 = bm + rowA0; if (gr0 >= M) gr0 = M - 1;
    int gr1 = bm + rowA1; if (gr1 >= M) gr1 = M - 1;
    const u16* a0p = A + (size_t)gr0 * lda + colE;
    const u16* a1p = A + (size_t)gr1 * lda + colE;
    const u16* b0p = Bt + (size_t)(bn + rowA0) * K + colE;
    const u16* b1p = Bt + (size_t)(bn + rowA1) * K + colE;
    u16* lA0 = As + c0 * 512;
    u16* lA1 = As + c0 * 512 + 512;
    u16* lB0 = Bs + c0 * 512;
    u16* lB1 = Bs + c0 * 512 + 512;

    for (int k0 = 0; k0 < K; k0 += 32) {
        __syncthreads();
        gload16(a0p + k0, lA0);
        gload16(a1p + k0, lA1);
        gload16(b0p + k0, lB0);
        gload16(b1p + k0, lB1);
        __syncthreads();
        short8 af[4], bf[4];
#pragma unroll
        for (int t = 0; t < 4; ++t) {
            af[t] = *(const short8*)&As[(wrow + t * 16 + l15) * 32 + l4 * 8];
            bf[t] = *(const short8*)&Bs[(wcol + t * 16 + l15) * 32 + l4 * 8];
        }
#pragma unroll
        for (int mi = 0; mi < 4; ++mi)
#pragma unroll
            for (int ni = 0; ni < 4; ++ni)
                acc[mi][ni] = __builtin_amdgcn_mfma_f32_16x16x32_bf16(
                    af[mi], bf[ni], acc[mi][ni], 0, 0, 0);
    }

#pragma unroll
    for (int mi = 0; mi < 4; ++mi)
#pragma unroll
        for (int ni = 0; ni < 4; ++ni)
#pragma unroll
            for (int r4 = 0; r4 < 4; ++r4) {
                int row = bm + wrow + mi * 16 + l4 * 4 + r4;
                int col = bn + wcol + ni * 16 + l15;
                if (row < M) {
                    float v = acc[mi][ni][r4];
                    if (bias && col < bias_n) v += bias[col];
                    if (relu) v = fmaxf(v, 0.0f);
                    if (C) C[(size_t)row * ldc + col] = f2b(v);
                    if (Cf) Cf[(size_t)row * ldc + col] = v;
                }
            }
}

// ---------------- 64x64 MFMA GEMM (kept for the N=64 FC layer) ----------------
__global__ __launch_bounds__(256) void gemm_k(
    const u16* __restrict__ A, const u16* __restrict__ Bt,
    u16* __restrict__ C, float* __restrict__ Cf,
    const float* __restrict__ bias, int bias_n, int relu,
    int M, int K, int lda, int ldc) {
    __shared__ u16 As[64][40];
    __shared__ u16 Bs[64][40];
    const int tid = threadIdx.x;
    const int wave = tid >> 6, lane = tid & 63;
    const int bm = blockIdx.x * 64, bn = blockIdx.y * 64;
    const int wr = (wave >> 1) * 32, wc = (wave & 1) * 32;
    const int l15 = lane & 15, l4 = lane >> 4;
    f32x4 acc[2][2] = {};

    const int srow = tid >> 2;
    const int skoff = (tid & 3) * 8;
    const bool arow_ok = (bm + srow) < M;
    const u16* aptr = A + (size_t)(bm + srow) * lda + skoff;
    const u16* bptr = Bt + (size_t)(bn + srow) * K + skoff;

    for (int k0 = 0; k0 < K; k0 += 32) {
        short8 av = {};
        if (arow_ok) av = *(const short8*)(aptr + k0);
        short8 bv = *(const short8*)(bptr + k0);
        __syncthreads();
        *(short8*)&As[srow][skoff] = av;
        *(short8*)&Bs[srow][skoff] = bv;
        __syncthreads();
        short8 a0 = *(const short8*)&As[wr + l15][l4 * 8];
        short8 a1 = *(const short8*)&As[wr + 16 + l15][l4 * 8];
        short8 bb0 = *(const short8*)&Bs[wc + l15][l4 * 8];
        short8 bb1 = *(const short8*)&Bs[wc + 16 + l15][l4 * 8];
        acc[0][0] = __builtin_amdgcn_mfma_f32_16x16x32_bf16(a0, bb0, acc[0][0], 0, 0, 0);
        acc[0][1] = __builtin_amdgcn_mfma_f32_16x16x32_bf16(a0, bb1, acc[0][1], 0, 0, 0);
        acc[1][0] = __builtin_amdgcn_mfma_f32_16x16x32_bf16(a1, bb0, acc[1][0], 0, 0, 0);
        acc[1][1] = __builtin_amdgcn_mfma_f32_16x16x32_bf16(a1, bb1, acc[1][1], 0, 0, 0);
    }

#pragma unroll
    for (int mi = 0; mi < 2; ++mi)
#pragma unroll
        for (int ni = 0; ni < 2; ++ni)
#pragma unroll
            for (int r = 0; r < 4; ++r) {
                int row = bm + wr + mi * 16 + l4 * 4 + r;
                int col = bn + wc + ni * 16 + l15;
                if (row < M) {
                    float v = acc[mi][ni][r];
                    if (bias && col < bias_n) v += bias[col];
                    if (relu) v = fmaxf(v, 0.0f);
                    if (C) C[(size_t)row * ldc + col] = f2b(v);
                    if (Cf) Cf[(size_t)row * ldc + col] = v;
                }
            }
}

// ---------------- fused width-400 spmm: one wave per row ----------------
// X: stride 640 u16, 400-col window. Y1 gets cols [0,200) (stride 640),
// Yt gets cols [200,400) (stride 200). bias1 (len 200) applies to Y1 only.
__global__ __launch_bounds__(256) void spmm400_k(
    const int* __restrict__ row_ptr, const int* __restrict__ cols,
    const float* __restrict__ vals, int E,
    const u16* __restrict__ X, u16* __restrict__ Y1, u16* __restrict__ Yt,
    const float* __restrict__ bias1) {
    int r = blockIdx.x * 4 + (threadIdx.x >> 6);
    if (r >= NN) return;
    int lane = threadIdx.x & 63;
    int s = row_ptr[r], e = row_ptr[r + 1];
    if (e > E) e = E;
    if (s < 0) s = 0;
    if (s > e) s = e;
    float a[8] = {0.f, 0.f, 0.f, 0.f, 0.f, 0.f, 0.f, 0.f};
    const bool act = lane < 50;
    const u32* xb = (const u32*)X;
    int i = s;
    for (; i + 2 <= e; i += 2) {
        int ca = cols[i]; if ((u32)ca >= NN) ca = 0;
        int cb = cols[i + 1]; if ((u32)cb >= NN) cb = 0;
        float va = vals[i], vb = vals[i + 1];
        if (act) {
            u32x4 ga = *(const u32x4*)(xb + (size_t)ca * 320 + lane * 4);
            u32x4 gb = *(const u32x4*)(xb + (size_t)cb * 320 + lane * 4);
#pragma unroll
            for (int q = 0; q < 4; ++q) {
                union { u32 i; float f; } lo, hi;
                lo.i = ga[q] << 16; hi.i = ga[q] & 0xffff0000u;
                a[2 * q] = fmaf(va, lo.f, a[2 * q]);
                a[2 * q + 1] = fmaf(va, hi.f, a[2 * q + 1]);
                lo.i = gb[q] << 16; hi.i = gb[q] & 0xffff0000u;
                a[2 * q] = fmaf(vb, lo.f, a[2 * q]);
                a[2 * q + 1] = fmaf(vb, hi.f, a[2 * q + 1]);
            }
        }
    }
    if (i < e) {
        int ca = cols[i]; if ((u32)ca >= NN) ca = 0;
        float va = vals[i];
        if (act) {
            u32x4 ga = *(const u32x4*)(xb + (size_t)ca * 320 + lane * 4);
#pragma unroll
            for (int q = 0; q < 4; ++q) {
                union { u32 i; float f; } lo, hi;
                lo.i = ga[q] << 16; hi.i = ga[q] & 0xffff0000u;
                a[2 * q] = fmaf(va, lo.f, a[2 * q]);
                a[2 * q + 1] = fmaf(va, hi.f, a[2 * q + 1]);
            }
        }
    }
    if (bias1 && lane < 25) {
#pragma unroll
        for (int q = 0; q < 8; ++q) a[q] += bias1[lane * 8 + q];
    }
    u32x4 o;
    o[0] = pack2(a[0], a[1]); o[1] = pack2(a[2], a[3]);
    o[2] = pack2(a[4], a[5]); o[3] = pack2(a[6], a[7]);
    if (lane < 25) {
        *(u32x4*)((u32*)Y1 + (size_t)r * 320 + lane * 4) = o;
    } else if (lane < 50) {
        *(u32x4*)((u32*)Yt + (size_t)r * 100 + (lane - 25) * 4) = o;
    }
}

// ---------------- width-200 spmm: one wave per row ----------------
__global__ __launch_bounds__(256) void spmm200_k(
    const int* __restrict__ row_ptr, const int* __restrict__ cols,
    const float* __restrict__ vals, int E,
    const u16* __restrict__ X, int ldx,
    u16* __restrict__ Y, int ldy,
    const float* __restrict__ bias) {
    int r = blockIdx.x * 4 + (threadIdx.x >> 6);
    if (r >= NN) return;
    int lane = threadIdx.x & 63;
    int s = row_ptr[r], e = row_ptr[r + 1];
    if (e > E) e = E;
    if (s < 0) s = 0;
    if (s > e) s = e;
    float a[4] = {0.f, 0.f, 0.f, 0.f};
    const bool act = lane < 50;
    const int ldxw = ldx >> 1, ldyw = ldy >> 1;
    const u32* xb = (const u32*)X;
    int i = s;
    for (; i + 2 <= e; i += 2) {
        int ca = cols[i]; if ((u32)ca >= NN) ca = 0;
        int cb = cols[i + 1]; if ((u32)cb >= NN) cb = 0;
        float va = vals[i], vb = vals[i + 1];
        if (act) {
            u32x2 ga = *(const u32x2*)(xb + (size_t)ca * ldxw + lane * 2);
            u32x2 gb = *(const u32x2*)(xb + (size_t)cb * ldxw + lane * 2);
#pragma unroll
            for (int q = 0; q < 2; ++q) {
                union { u32 i; float f; } lo, hi;
                lo.i = ga[q] << 16; hi.i = ga[q] & 0xffff0000u;
                a[2 * q] = fmaf(va, lo.f, a[2 * q]);
                a[2 * q + 1] = fmaf(va, hi.f, a[2 * q + 1]);
                lo.i = gb[q] << 16; hi.i = gb[q] & 0xffff0000u;
                a[2 * q] = fmaf(vb, lo.f, a[2 * q]);
                a[2 * q + 1] = fmaf(vb, hi.f, a[2 * q + 1]);
            }
        }
    }
    if (i < e) {
        int ca = cols[i]; if ((u32)ca >= NN) ca = 0;
        float va = vals[i];
        if (act) {
            u32x2 ga = *(const u32x2*)(xb + (size_t)ca * ldxw + lane * 2);
#pragma unroll
            for (int q = 0; q < 2; ++q) {
                union { u32 i; float f; } lo, hi;
                lo.i = ga[q] << 16; hi.i = ga[q] & 0xffff0000u;
                a[2 * q] = fmaf(va, lo.f, a[2 * q]);
                a[2 * q + 1] = fmaf(va, hi.f, a[2 * q + 1]);
            }
        }
    }
    if (bias && act) {
#pragma unroll
        for (int q = 0; q < 4; ++q) a[q] += bias[lane * 4 + q];
    }
    if (act) {
        u32x2 o;
        o[0] = pack2(a[0], a[1]); o[1] = pack2(a[2], a[3]);
        *(u32x2*)((u32*)Y + (size_t)r * ldyw + lane * 2) = o;
    }
}

// ---------------- copies ----------------
__global__ void copyblk_k(const u16* __restrict__ src, u16* __restrict__ dst) {
    int i = blockIdx.x * 256 + threadIdx.x;
    if (i >= NN * 100) return;
    int r = i / 100, c = i % 100;
    ((u32*)dst)[(size_t)r * 320 + c] = ((const u32*)src)[(size_t)r * 320 + c];
}
__global__ void zeropad_k(u16* __restrict__ dst) {
    int i = blockIdx.x * 256 + threadIdx.x;
    if (i >= NN * 20) return;
    int r = i / 20, c = i % 20;
    ((u32*)dst)[(size_t)r * 320 + 300 + c] = 0u;
}
__global__ void copybias_k(const u16* __restrict__ src, u16* __restrict__ dst,
                           const float* __restrict__ bias) {
    int i = blockIdx.x * 256 + threadIdx.x;
    if (i >= NN * 200) return;
    int r = i / 200, c = i % 200;
    dst[(size_t)r * 640 + c] = f2b(b2f(src[(size_t)r * 640 + c]) + bias[c]);
}

// ---------------- log_softmax over 64 classes, one wave per row (fp32 in/out) -----------
__global__ void softmax_k(const float* __restrict__ ne, float* __restrict__ out) {
    int r = blockIdx.x * 4 + (threadIdx.x >> 6);
    if (r >= NN) return;
    int lane = threadIdx.x & 63;
    float v = ne[(size_t)r * 64 + lane];
    float m = v;
    for (int off = 32; off; off >>= 1) m = fmaxf(m, __shfl_xor(m, off, 64));
    float e = expf(v - m);
    float ssum = e;
    for (int off = 32; off; off >>= 1) ssum += __shfl_xor(ssum, off, 64);
    out[(size_t)r * 64 + lane] = v - m - logf(ssum);
}

extern "C" void kernel_launch(void* const* d_in, const int* in_sizes, int n_in,
                              void* d_out, int out_size, void* d_ws, size_t ws_size,
                              hipStream_t stream) {
    const int* adj_idx = (const int*)d_in[0];
    const void* adj_vals = d_in[1];
    const void* feats = d_in[2];
    const void* W1 = d_in[3];
    const void* b1 = d_in[4];
    const void* W2 = d_in[5];
    const void* b2 = d_in[6];
    const void* Wfc = d_in[7];
    const void* bfc = d_in[8];
    const int E = in_sizes[1];
    (void)n_in; (void)out_size; (void)ws_size;

    char* ws = (char*)d_ws;
    size_t off = 0;
    auto alloc = [&](size_t b) { size_t o = off; off += (b + 255) & ~(size_t)255; return o; };
    u16* buf0 = (u16*)(ws + alloc((size_t)NN * PAD * 2));   // U, then V
    u16* buf1 = (u16*)(ws + alloc((size_t)NN * PAD * 2));   // featsB, abstract1, abstract2
    u16* hop = (u16*)(ws + alloc((size_t)NN * 200 * 2));
    u16* w1t = (u16*)(ws + alloc((size_t)640 * 512 * 2));
    u16* w2t = (u16*)(ws + alloc((size_t)640 * 640 * 2));
    u16* wfct = (u16*)(ws + alloc((size_t)64 * 640 * 2));
    float* biasf = (float*)(ws + alloc(1264 * 4));
    int* counts = (int*)(ws + alloc((size_t)NN * 4));
    int* cursor = (int*)(ws + alloc((size_t)NN * 4));
    int* row_ptr = (int*)(ws + alloc((size_t)(NN + 1) * 4));
    int* chsum = (int*)(ws + alloc(4096));
    int* choff = (int*)(ws + alloc(4096));
    int* flags = (int*)(ws + alloc(256));
    int* colsS = (int*)(ws + alloc((size_t)E * 4));
    float* valsS = (float*)(ws + alloc((size_t)E * 4));

    u16* featsB = buf1;  // alias: featsB dead after GEMM1, buf1 written after
    float* out_ne = (float*)d_out;              // fp32 node_emb
    float* out_pred = out_ne + (size_t)NN * 64; // fp32 log-softmax

    // probes + canonicalization
    probe_k<<<1, 64, 0, stream>>>(adj_idx, adj_vals, feats, W1, b1, W2, b2, Wfc, bfc, flags);
    featconv_k<<<(NN * 512 + 255) / 256, 256, 0, stream>>>(feats, featsB, flags);
    w1t_k<<<(640 * 512 + 255) / 256, 256, 0, stream>>>(W1, w1t, flags);
    w2t_k<<<(640 * 640 + 255) / 256, 256, 0, stream>>>(W2, w2t, flags);
    wfct_k<<<(64 * 640 + 255) / 256, 256, 0, stream>>>(Wfc, wfct, flags);
    bconv_k<<<5, 256, 0, stream>>>(b1, b2, bfc, biasf, flags);

    // CSR build
    hipMemsetAsync(counts, 0, NN * 4, stream);
    count_k<<<(E + 255) / 256, 256, 0, stream>>>(adj_idx, E, flags, counts);
    const int NCH = (NN + 1023) / 1024;  // 98
    chunksum_k<<<NCH, 256, 0, stream>>>(counts, chsum);
    chscan_k<<<1, 64, 0, stream>>>(chsum, NCH, choff, row_ptr, E);
    scan_k<<<NCH, 1024, 0, stream>>>(counts, choff, row_ptr, cursor);
    scatter_k<<<(E + 255) / 256, 256, 0, stream>>>(adj_idx, adj_vals, E, flags, cursor, colsS, valsS);

    dim3 g128((NN + 127) / 128, PAD / 128);  // (782, 5)
    // U = relu(X @ W1all + b1) -> buf0
    gemm128_k<<<g128, 256, 0, stream>>>(featsB, w1t, buf0, nullptr, biasf, 600, 1, NN, 512, 512, PAD);
    // abstract1 -> buf1: block0 copy + pad zero; hop1 (width 400 fused) + hop2
    copyblk_k<<<(NN * 100 + 255) / 256, 256, 0, stream>>>(buf0, buf1);
    zeropad_k<<<(NN * 20 + 255) / 256, 256, 0, stream>>>(buf1);
    spmm400_k<<<(NN + 3) / 4, 256, 0, stream>>>(row_ptr, colsS, valsS, E,
                                                buf0 + 200, buf1 + 200, hop, nullptr);
    spmm200_k<<<(NN + 3) / 4, 256, 0, stream>>>(row_ptr, colsS, valsS, E,
                                                hop, 200, buf1 + 400, PAD, nullptr);
    // V = abstract1 @ W2all -> buf0
    gemm128_k<<<g128, 256, 0, stream>>>(buf1, w2t, buf0, nullptr, nullptr, 0, 0, NN, PAD, PAD, PAD);
    // abstract2 -> buf1
    copybias_k<<<(NN * 200 + 255) / 256, 256, 0, stream>>>(buf0, buf1, biasf + 600);
    spmm400_k<<<(NN + 3) / 4, 256, 0, stream>>>(row_ptr, colsS, valsS, E,
                                                buf0 + 200, buf1 + 200, hop, biasf + 800);
    spmm200_k<<<(NN + 3) / 4, 256, 0, stream>>>(row_ptr, colsS, valsS, E,
                                                hop, 200, buf1 + 400, PAD, biasf + 1000);
    // node_emb = abstract2 @ Wfc + bfc -> d_out (fp32)
    dim3 gC((NN + 63) / 64, 1);
    gemm_k<<<gC, 256, 0, stream>>>(buf1, wfct, nullptr, out_ne, biasf + 1200, 64, 0, NN, PAD, PAD, 64);
    // predictions = log_softmax(node_emb) (fp32)
    softmax_k<<<(NN + 3) / 4, 256, 0, stream>>>(out_ne, out_pred);
}